// Round 1
// baseline (3183.673 us; speedup 1.0000x reference)
//
#include <hip/hip_runtime.h>
#include <hip/hip_bf16.h>
#include <cmath>

#define DEVI __device__ __forceinline__

constexpr int Hn   = 2048;   // hidden
constexpr int In   = 1408;   // per-expert intermediate
constexpr int En   = 16;     // routed experts
constexpr int Kn   = 4;      // top-k
constexpr int ISHn = 2816;   // shared intermediate
constexpr int Tn   = 8192;   // tokens (B*S)

typedef __attribute__((ext_vector_type(4))) float f32x4;
typedef __attribute__((ext_vector_type(8))) __bf16 bf16x8;
typedef __attribute__((ext_vector_type(8))) unsigned short u16x8;

DEVI unsigned short f2bf(float f) {
  unsigned int u = __builtin_bit_cast(unsigned int, f);
  unsigned int r = (u + 0x7fffu + ((u >> 16) & 1u)) >> 16;
  return (unsigned short)r;
}

DEVI f32x4 mfma16(bf16x8 a, bf16x8 b, f32x4 c) {
  return __builtin_amdgcn_mfma_f32_16x16x32_bf16(a, b, c, 0, 0, 0);
}

DEVI bf16x8 lds_frag(const unsigned short* p) {
  return __builtin_bit_cast(bf16x8, *reinterpret_cast<const u16x8*>(p));
}

DEVI void gload_lds16(const void* src, void* dst) {
  __builtin_amdgcn_global_load_lds(
      (const __attribute__((address_space(1))) void*)src,
      (__attribute__((address_space(3))) void*)dst, 16, 0, 0);
}

DEVI void pack8(unsigned short* dst, float4 a, float4 b) {
  u16x8 v;
  v[0] = f2bf(a.x); v[1] = f2bf(a.y); v[2] = f2bf(a.z); v[3] = f2bf(a.w);
  v[4] = f2bf(b.x); v[5] = f2bf(b.y); v[6] = f2bf(b.z); v[7] = f2bf(b.w);
  *reinterpret_cast<u16x8*>(dst) = v;
}

// ---------------- x -> bf16 ----------------
__global__ void cvt_x(const float* __restrict__ x, unsigned short* __restrict__ xb) {
  constexpr int Nv = Tn * Hn / 4;
  int stride = gridDim.x * blockDim.x;
  for (int v = blockIdx.x * blockDim.x + threadIdx.x; v < Nv; v += stride) {
    float4 a = reinterpret_cast<const float4*>(x)[v];
    ushort4 o;
    o.x = f2bf(a.x); o.y = f2bf(a.y); o.z = f2bf(a.z); o.w = f2bf(a.w);
    reinterpret_cast<ushort4*>(xb)[v] = o;
  }
}

// ---------------- zero counts + cursor (32 ints contiguous) ----------------
__global__ void zero_k(int* p) { p[threadIdx.x] = 0; }

// ---------------- router: one wave per token, fp64 scoring ----------------
__global__ __launch_bounds__(256)
void router_k(const float* __restrict__ x, const float* __restrict__ rg,
              const float* __restrict__ ru, const float* __restrict__ esc,
              const float* __restrict__ ebi, int* __restrict__ counts,
              int* __restrict__ topk, float* __restrict__ wval) {
  int w = (blockIdx.x * blockDim.x + threadIdx.x) >> 6;
  int lane = threadIdx.x & 63;
  if (w >= Tn) return;
  const float* xr = x + (size_t)w * Hn;
  float xv[Hn / 64];
#pragma unroll
  for (int j = 0; j < Hn / 64; ++j) xv[j] = xr[lane + j * 64];

  double pr[En];
  double mx = -1e300;
#pragma unroll
  for (int e = 0; e < En; ++e) {
    const float* gr = rg + (size_t)e * Hn;
    const float* ur = ru + (size_t)e * Hn;
    double pg = 0.0, pu = 0.0;
#pragma unroll
    for (int j = 0; j < Hn / 64; ++j) {
      pg += (double)xv[j] * (double)gr[lane + j * 64];
      pu += (double)xv[j] * (double)ur[lane + j * 64];
    }
#pragma unroll
    for (int s = 32; s > 0; s >>= 1) {
      pg += __shfl_xor(pg, s);
      pu += __shfl_xor(pu, s);
    }
    double sg = pg / (1.0 + exp(-pg));     // silu
    double sc = fabs(pu * sg);
    pr[e] = sc;
    mx = fmax(mx, sc);
  }
  // softmax (monotonic; ordering == score ordering)
  double den = 0.0;
#pragma unroll
  for (int e = 0; e < En; ++e) { pr[e] = exp(pr[e] - mx); den += pr[e]; }

  if (lane == 0) {
    double invden = 1.0 / den;
    unsigned chosen = 0;
    for (int k = 0; k < Kn; ++k) {
      double bv = -1e300; int best = 0;
#pragma unroll
      for (int e = 0; e < En; ++e) {
        double be = pr[e] * invden + (double)ebi[e];
        if (!((chosen >> e) & 1u) && be > bv) { bv = be; best = e; }
      }
      chosen |= 1u << best;
      topk[w * Kn + k] = best;
      double pbest = bv - (double)ebi[best];
      wval[w * Kn + k] = (float)(1.0 + pbest * (double)esc[best]);
      atomicAdd(&counts[best], 1);
    }
  }
}

// ---------------- prefix over expert counts ----------------
__global__ void prefix_k(const int* __restrict__ counts, int* __restrict__ off) {
  if (threadIdx.x == 0) {
    int a = 0;
    for (int e = 0; e < En; ++e) { off[e] = a; a += counts[e]; }
    off[En] = a;
  }
}

// ---------------- build per-expert token lists ----------------
__global__ void build_k(const int* __restrict__ topk, const float* __restrict__ wval,
                        const int* __restrict__ off, int* __restrict__ cursor,
                        int* __restrict__ list, float* __restrict__ cw) {
  int t = blockIdx.x * blockDim.x + threadIdx.x;
  if (t >= Tn) return;
  for (int k = 0; k < Kn; ++k) {
    int e = topk[t * Kn + k];
    int pos = atomicAdd(&cursor[e], 1);
    int r = off[e] + pos;
    list[r] = t;
    cw[r] = wval[t * Kn + k];
  }
}

// ---------------- up-proj: h = silu(A@Wg^T) * (A@Wu^T), A gathered ----------------
template <bool SHARED>
__global__ __launch_bounds__(256, 2)
void up_k(const unsigned short* __restrict__ xb,
          const float* __restrict__ Wgp, const float* __restrict__ Wup,
          const int* __restrict__ list, const int* __restrict__ off,
          const int* __restrict__ counts,
          unsigned short* __restrict__ hbuf, int Ncols) {
  int cnt, offE;
  const float *wg, *wu;
  if constexpr (SHARED) {
    cnt = Tn; offE = 0; wg = Wgp; wu = Wup;
  } else {
    int e = blockIdx.z;
    cnt = counts[e];
    offE = off[e];
    wg = Wgp + (size_t)e * In * Hn;
    wu = Wup + (size_t)e * In * Hn;
  }
  int m0 = blockIdx.x * 128;
  if (m0 >= cnt) return;
  int n0 = blockIdx.y * 64;

  __shared__ alignas(16) unsigned short As[128 * 64];
  __shared__ alignas(16) unsigned short Bg[64 * 64];
  __shared__ alignas(16) unsigned short Bu[64 * 64];

  int tid = threadIdx.x;
  int lane = tid & 63;
  int wv = tid >> 6;
  int wm = wv >> 1, wn = wv & 1;

  const unsigned short* gA[4];
#pragma unroll
  for (int i = 0; i < 4; ++i) {
    int idx = i * 256 + tid;
    int row = idx >> 3, ch = idx & 7;
    int rc = m0 + row; rc = rc < cnt ? rc : cnt - 1;
    int tok;
    if constexpr (SHARED) tok = m0 + row;       // grid exact, < Tn
    else tok = list[offE + rc];
    gA[i] = xb + (size_t)tok * Hn + ch * 8;
  }
  int brow = tid >> 2, bq = tid & 3;
  const float* wgp = wg + (size_t)(n0 + brow) * Hn + bq * 16;
  const float* wup = wu + (size_t)(n0 + brow) * Hn + bq * 16;
  unsigned short* bgs = &Bg[brow * 64 + bq * 16];
  unsigned short* bus = &Bu[brow * 64 + bq * 16];

  f32x4 accg[4][2], accu[4][2];
#pragma unroll
  for (int m = 0; m < 4; ++m)
#pragma unroll
    for (int n = 0; n < 2; ++n) {
      accg[m][n] = f32x4{0.f, 0.f, 0.f, 0.f};
      accu[m][n] = f32x4{0.f, 0.f, 0.f, 0.f};
    }

  for (int kb = 0; kb < Hn / 64; ++kb) {
#pragma unroll
    for (int i = 0; i < 4; ++i)
      gload_lds16(gA[i] + kb * 64, &As[i * 2048 + wv * 512]);
    {
      const float4* s = reinterpret_cast<const float4*>(wgp + kb * 64);
      pack8(bgs, s[0], s[1]);
      pack8(bgs + 8, s[2], s[3]);
      const float4* s2 = reinterpret_cast<const float4*>(wup + kb * 64);
      pack8(bus, s2[0], s2[1]);
      pack8(bus + 8, s2[2], s2[3]);
    }
    __syncthreads();
#pragma unroll
    for (int kk = 0; kk < 2; ++kk) {
      int klo = kk * 32 + (lane >> 4) * 8;
      bf16x8 a[4], bg2[2], bu2[2];
#pragma unroll
      for (int m = 0; m < 4; ++m)
        a[m] = lds_frag(&As[(wm * 64 + m * 16 + (lane & 15)) * 64 + klo]);
#pragma unroll
      for (int n = 0; n < 2; ++n) {
        bg2[n] = lds_frag(&Bg[(wn * 32 + n * 16 + (lane & 15)) * 64 + klo]);
        bu2[n] = lds_frag(&Bu[(wn * 32 + n * 16 + (lane & 15)) * 64 + klo]);
      }
#pragma unroll
      for (int m = 0; m < 4; ++m)
#pragma unroll
        for (int n = 0; n < 2; ++n) {
          accg[m][n] = mfma16(a[m], bg2[n], accg[m][n]);
          accu[m][n] = mfma16(a[m], bu2[n], accu[m][n]);
        }
    }
    __syncthreads();
  }

#pragma unroll
  for (int m = 0; m < 4; ++m) {
#pragma unroll
    for (int j = 0; j < 4; ++j) {
      int r = wm * 64 + m * 16 + (lane >> 4) * 4 + j;
      if (m0 + r < cnt) {
#pragma unroll
        for (int n = 0; n < 2; ++n) {
          int col = n0 + wn * 32 + n * 16 + (lane & 15);
          float g = accg[m][n][j], u = accu[m][n][j];
          float h = (g / (1.f + __expf(-g))) * u;
          hbuf[(size_t)(offE + m0 + r) * Ncols + col] = f2bf(h);
        }
      }
    }
  }
}

// ---------------- down-proj: C = h @ Wd^T, scatter(+coef) ----------------
template <bool SHARED>
__global__ __launch_bounds__(256, 2)
void down_k(const unsigned short* __restrict__ hbuf,
            const float* __restrict__ Wdp,
            const int* __restrict__ list, const int* __restrict__ off,
            const int* __restrict__ counts, const float* __restrict__ cw,
            float* __restrict__ out, int Kdim) {
  int cnt, offE;
  const float* wd;
  if constexpr (SHARED) { cnt = Tn; offE = 0; wd = Wdp; }
  else {
    int e = blockIdx.z;
    cnt = counts[e]; offE = off[e];
    wd = Wdp + (size_t)e * Hn * In;
  }
  int m0 = blockIdx.x * 128;
  if (m0 >= cnt) return;
  int n0 = blockIdx.y * 128;

  __shared__ alignas(16) unsigned short As[128 * 64];
  __shared__ alignas(16) unsigned short Bs[128 * 64];

  int tid = threadIdx.x, lane = tid & 63, wv = tid >> 6;
  int wm = wv >> 1, wn = wv & 1;

  const unsigned short* gA[4];
#pragma unroll
  for (int i = 0; i < 4; ++i) {
    int idx = i * 256 + tid;
    int row = idx >> 3, ch = idx & 7;
    gA[i] = hbuf + (size_t)(offE + m0 + row) * Kdim + ch * 8;
  }
  int brow = tid >> 1, bh = tid & 1;
  const float* wdp = wd + (size_t)(n0 + brow) * Kdim + bh * 32;
  unsigned short* bsp = &Bs[brow * 64 + bh * 32];

  f32x4 acc[4][4];
#pragma unroll
  for (int m = 0; m < 4; ++m)
#pragma unroll
    for (int n = 0; n < 4; ++n) acc[m][n] = f32x4{0.f, 0.f, 0.f, 0.f};

  int nkb = Kdim / 64;
  for (int kb = 0; kb < nkb; ++kb) {
#pragma unroll
    for (int i = 0; i < 4; ++i)
      gload_lds16(gA[i] + kb * 64, &As[i * 2048 + wv * 512]);
    {
      const float4* s = reinterpret_cast<const float4*>(wdp + kb * 64);
#pragma unroll
      for (int q = 0; q < 4; ++q)
        pack8(bsp + q * 8, s[q * 2], s[q * 2 + 1]);
    }
    __syncthreads();
#pragma unroll
    for (int kk = 0; kk < 2; ++kk) {
      int klo = kk * 32 + (lane >> 4) * 8;
      bf16x8 a[4], b[4];
#pragma unroll
      for (int m = 0; m < 4; ++m)
        a[m] = lds_frag(&As[(wm * 64 + m * 16 + (lane & 15)) * 64 + klo]);
#pragma unroll
      for (int n = 0; n < 4; ++n)
        b[n] = lds_frag(&Bs[(wn * 64 + n * 16 + (lane & 15)) * 64 + klo]);
#pragma unroll
      for (int m = 0; m < 4; ++m)
#pragma unroll
        for (int n = 0; n < 4; ++n)
          acc[m][n] = mfma16(a[m], b[n], acc[m][n]);
    }
    __syncthreads();
  }

#pragma unroll
  for (int m = 0; m < 4; ++m) {
#pragma unroll
    for (int j = 0; j < 4; ++j) {
      int r = wm * 64 + m * 16 + (lane >> 4) * 4 + j;
      if (m0 + r < cnt) {
        int tok; float coef;
        if constexpr (SHARED) { tok = m0 + r; coef = 1.f; }
        else { tok = list[offE + m0 + r]; coef = cw[offE + m0 + r]; }
#pragma unroll
        for (int n = 0; n < 4; ++n) {
          int col = n0 + wn * 64 + n * 16 + (lane & 15);
          float v = acc[m][n][j] * coef;
          if constexpr (SHARED) out[(size_t)tok * Hn + col] = v;
          else atomicAdd(&out[(size_t)tok * Hn + col], v);
        }
      }
    }
  }
}

extern "C" void kernel_launch(void* const* d_in, const int* in_sizes, int n_in,
                              void* d_out, int out_size, void* d_ws, size_t ws_size,
                              hipStream_t stream) {
  const float* x   = (const float*)d_in[0];
  const float* rg  = (const float*)d_in[1];
  const float* ru  = (const float*)d_in[2];
  const float* esc = (const float*)d_in[3];
  const float* ebi = (const float*)d_in[4];
  const float* Wg  = (const float*)d_in[5];
  const float* Wu  = (const float*)d_in[6];
  const float* Wd  = (const float*)d_in[7];
  const float* Sg  = (const float*)d_in[8];
  const float* Su  = (const float*)d_in[9];
  const float* Sd  = (const float*)d_in[10];
  float* out = (float*)d_out;

  char* ws = (char*)d_ws;
  // layout
  const size_t sz_xb  = (size_t)Tn * Hn * 2;                    // 33,554,432
  const size_t sz_hrt = (size_t)(Tn * Kn + 128) * In * 2;       // 92,635,136
  const size_t sz_hsh = (size_t)(Tn + 128) * ISHn * 2;          // 46,858,240
  unsigned short* xb  = (unsigned short*)(ws);
  unsigned short* hrt = (unsigned short*)(ws + sz_xb);
  unsigned short* hsh = (unsigned short*)(ws + sz_xb + sz_hrt);
  char* misc = ws + sz_xb + sz_hrt + sz_hsh;
  int*   counts = (int*)(misc);
  int*   cursor = (int*)(misc + 64);
  int*   off    = (int*)(misc + 128);
  int*   topk   = (int*)(misc + 256);
  float* wval   = (float*)(misc + 256 + 131072);
  int*   list   = (int*)(misc + 256 + 2 * 131072);
  float* cw     = (float*)(misc + 256 + 3 * 131072);

  zero_k<<<1, 32, 0, stream>>>(counts);  // counts[16] + cursor[16] contiguous
  cvt_x<<<2048, 256, 0, stream>>>(x, xb);
  router_k<<<2048, 256, 0, stream>>>(x, rg, ru, esc, ebi, counts, topk, wval);
  prefix_k<<<1, 64, 0, stream>>>(counts, off);
  build_k<<<Tn / 256, 256, 0, stream>>>(topk, wval, off, cursor, list, cw);

  up_k<false><<<dim3(64, In / 64, En), 256, 0, stream>>>(xb, Wg, Wu, list, off, counts, hrt, In);
  up_k<true><<<dim3(Tn / 128, ISHn / 64, 1), 256, 0, stream>>>(xb, Sg, Su, nullptr, nullptr, nullptr, hsh, ISHn);
  // shared down writes out with plain stores (must precede routed atomics)
  down_k<true><<<dim3(Tn / 128, Hn / 128, 1), 256, 0, stream>>>(hsh, Sd, nullptr, nullptr, nullptr, nullptr, out, ISHn);
  down_k<false><<<dim3(64, Hn / 128, En), 256, 0, stream>>>(hrt, Wd, list, off, counts, cw, out, In);
}